// Round 1
// 530.829 us; speedup vs baseline: 1.0288x; 1.0288x over previous
//
#include <hip/hip_runtime.h>

#define N_NODES 200000
#define DIM 480            // 120 float4 per row
#define N_SEG 4096
#define VEC (DIM / 4)      // 120
#define CHUNK 8            // rows in flight per row-slot
#define ROWSLOTS 2         // row-slots per block (256 threads = 2 x 128)

// 1) histogram of labels into counts[N_SEG]; also record each node's rank
//    within its segment so the scatter pass needs no atomics.
__global__ void hist_kernel(const int* __restrict__ labels,
                            int* __restrict__ counts,
                            int* __restrict__ rank, int n) {
    int i = blockIdx.x * blockDim.x + threadIdx.x;
    if (i < n) rank[i] = atomicAdd(&counts[labels[i]], 1);
}

// 2) exclusive scan of counts[4096] -> offsets[4096]; 1 block, 256 thr x 16.
//    offsets stays immutable (scatter no longer bumps it).
__global__ void scan_kernel(const int* __restrict__ counts,
                            int* __restrict__ offsets) {
    __shared__ int part[256];
    int t = threadIdx.x;
    int local[16];
    int base = t * 16;
    int sum = 0;
#pragma unroll
    for (int i = 0; i < 16; ++i) { local[i] = counts[base + i]; sum += local[i]; }
    part[t] = sum;
    __syncthreads();
    for (int off = 1; off < 256; off <<= 1) {
        int add = (t >= off) ? part[t - off] : 0;
        __syncthreads();
        part[t] += add;
        __syncthreads();
    }
    int excl = (t == 0) ? 0 : part[t - 1];
#pragma unroll
    for (int i = 0; i < 16; ++i) { offsets[base + i] = excl; excl += local[i]; }
}

// 3) counting-sort scatter, atomic-free: position = segment base + node rank.
__global__ void scatter_kernel(const int* __restrict__ labels,
                               const int* __restrict__ offsets,
                               const int* __restrict__ rank,
                               int* __restrict__ sorted_idx, int n) {
    int i = blockIdx.x * blockDim.x + threadIdx.x;
    if (i < n) sorted_idx[offsets[labels[i]] + rank[i]] = i;
}

// 4) per-segment gather + mean. 256 threads = 2 row-slots x 128 lanes,
//    CHUNK=8 rows per slot -> 16 independent row loads in flight per block.
//    Tail handled with clamped index + 0/1 weight (no divergent loop exit).
__global__ __launch_bounds__(256) void gather_mean_kernel(
    const float* __restrict__ x,
    const int* __restrict__ sorted_idx,
    const int* __restrict__ counts,
    const int* __restrict__ offsets,
    float* __restrict__ out) {
    int s = blockIdx.x;
    int cnt = counts[s];
    int start = offsets[s];
    int end = start + cnt;
    int t = threadIdx.x;
    int slot = t >> 7;        // 0 or 1
    int lane = t & 127;       // 0..127, active if < VEC

    __shared__ float4 red[VEC];

    float4 acc = make_float4(0.f, 0.f, 0.f, 0.f);
    if (lane < VEC) {
        for (int j0 = start + slot * CHUNK; j0 < end; j0 += ROWSLOTS * CHUNK) {
            // 8 independent uniform index loads (scalar/broadcast, L2-hot);
            // clamp keeps them valid, weight zeroes the overshoot.
            int   idx[CHUNK];
            float w[CHUNK];
#pragma unroll
            for (int k = 0; k < CHUNK; ++k) {
                int jj = j0 + k;
                w[k]   = (jj < end) ? 1.0f : 0.0f;
                idx[k] = sorted_idx[(jj < end) ? jj : start];
            }
            // 8 independent 16B row loads in flight per slot
            float4 v[CHUNK];
#pragma unroll
            for (int k = 0; k < CHUNK; ++k) {
                const float4* row = (const float4*)(x + (size_t)idx[k] * DIM);
                v[k] = row[lane];
            }
#pragma unroll
            for (int k = 0; k < CHUNK; ++k) {
                acc.x = fmaf(w[k], v[k].x, acc.x);
                acc.y = fmaf(w[k], v[k].y, acc.y);
                acc.z = fmaf(w[k], v[k].z, acc.z);
                acc.w = fmaf(w[k], v[k].w, acc.w);
            }
        }
    }

    // cross-slot reduction: slot1 -> LDS, slot0 combines + writes.
    if (slot == 1 && lane < VEC) red[lane] = acc;
    __syncthreads();
    if (slot == 0 && lane < VEC) {
        float4 o = red[lane];
        float inv = (cnt > 0) ? (1.0f / (float)cnt) : 0.0f;
        float4 r;
        r.x = (acc.x + o.x) * inv;
        r.y = (acc.y + o.y) * inv;
        r.z = (acc.z + o.z) * inv;
        r.w = (acc.w + o.w) * inv;
        ((float4*)(out + (size_t)s * DIM))[lane] = r;
    }
}

extern "C" void kernel_launch(void* const* d_in, const int* in_sizes, int n_in,
                              void* d_out, int out_size, void* d_ws, size_t ws_size,
                              hipStream_t stream) {
    const float* x      = (const float*)d_in[0];
    const int*   labels = (const int*)d_in[1];
    float* out = (float*)d_out;

    // workspace layout: counts[4096] | offsets[4096] | rank[200000] | sorted_idx[200000]
    int* counts     = (int*)d_ws;
    int* offsets    = counts + N_SEG;
    int* rank       = offsets + N_SEG;
    int* sorted_idx = rank + N_NODES;

    hipMemsetAsync(counts, 0, N_SEG * sizeof(int), stream);

    hist_kernel<<<(N_NODES + 255) / 256, 256, 0, stream>>>(labels, counts, rank,
                                                           N_NODES);
    scan_kernel<<<1, 256, 0, stream>>>(counts, offsets);
    scatter_kernel<<<(N_NODES + 255) / 256, 256, 0, stream>>>(labels, offsets,
                                                              rank, sorted_idx,
                                                              N_NODES);
    gather_mean_kernel<<<N_SEG, 256, 0, stream>>>(x, sorted_idx, counts, offsets,
                                                  out);
}